// Round 2
// baseline (334.771 us; speedup 1.0000x reference)
//
#include <hip/hip_runtime.h>
#include <hip/hip_bf16.h>

#define NN 16384
#define CD 32   // B*FNEW packed columns

typedef __attribute__((ext_vector_type(4))) float  f32x4;
typedef __attribute__((ext_vector_type(8))) short  s16x8;

__device__ inline short bf16_of(float f) {
    return __builtin_bit_cast(short, __float2bfloat16(f));
}

// Kernel 1: HpT[c][m] (bf16), c = b*16+g.  h[b,m,g] = sum_f x[b,m,f]*ker[m,f,g]
__global__ void fuse_h(const float* __restrict__ x, const float* __restrict__ ker,
                       __hip_bfloat16* __restrict__ hpt) {
    int tid = blockIdx.x * 256 + threadIdx.x;
    int g = tid & 15;
    int m = tid >> 4;            // 0..16383
    const float* xb0 = x + m * 16;
    const float* xb1 = x + NN * 16 + m * 16;
    const float* kp  = ker + m * 256 + g;
    float h0 = 0.f, h1 = 0.f;
#pragma unroll
    for (int f = 0; f < 16; ++f) {
        float kk = kp[f * 16];
        h0 += xb0[f] * kk;
        h1 += xb1[f] * kk;
    }
    hpt[g * NN + m]        = __float2bfloat16(h0);
    hpt[(16 + g) * NN + m] = __float2bfloat16(h1);
}

// Kernel 2: out[b,n,g] = sum_m A[n,m]*Hp[m,c] + bias[n,g]
// 512 thr = 8 waves; block owns 16 rows; wave w handles K-slice [w*2048,(w+1)*2048)
// launch_bounds(512,8): cap VGPR at 64 -> 8 waves/SIMD -> 32 waves/CU (HW max).
__global__ __launch_bounds__(512, 8) void gcn_main(
        const float* __restrict__ A,
        const __hip_bfloat16* __restrict__ hpt,
        const float* __restrict__ bias,
        float* __restrict__ out) {
    __shared__ float red[8][16][32];

    const int lane = threadIdx.x & 63;
    const int wave = threadIdx.x >> 6;   // 0..7
    const int n0   = blockIdx.x * 16;
    const int row  = lane & 15;          // A row within tile / B col within tile
    const int kg   = lane >> 4;          // 0..3 k-group

    f32x4 acc0 = {0.f, 0.f, 0.f, 0.f};
    f32x4 acc1 = {0.f, 0.f, 0.f, 0.f};

    const int kbase = wave * 2048;
    const float* ap = A + (size_t)(n0 + row) * NN + kbase + kg * 8;
    const __hip_bfloat16* b0 = hpt + row * NN + kbase + kg * 8;        // col-tile 0 (b=0)
    const __hip_bfloat16* b1 = hpt + (16 + row) * NN + kbase + kg * 8; // col-tile 1 (b=1)

    for (int kk = 0; kk < 2048; kk += 32) {
        // A fragment (fp32 -> bf16), one k-step of 32; non-temporal (A is
        // streamed exactly once -- keep hpt resident in L2)
        f32x4 p0 = __builtin_nontemporal_load((const f32x4*)ap);
        f32x4 p1 = __builtin_nontemporal_load((const f32x4*)(ap + 4));
        s16x8 a0;
#pragma unroll
        for (int i = 0; i < 4; ++i) {
            a0[i]     = bf16_of(p0[i]);
            a0[4 + i] = bf16_of(p1[i]);
        }
        // B fragments: single b128 loads from transposed bf16 HpT (L2-hot)
        s16x8 b00 = *(const s16x8*)(b0);
        s16x8 b10 = *(const s16x8*)(b1);

        acc0 = __builtin_amdgcn_mfma_f32_16x16x32_bf16(a0, b00, acc0, 0, 0, 0);
        acc1 = __builtin_amdgcn_mfma_f32_16x16x32_bf16(a0, b10, acc1, 0, 0, 0);

        ap += 32; b0 += 32; b1 += 32;
    }

    // D mapping: col = lane&15, row = (lane>>4)*4 + i
    const int r0 = kg * 4;
#pragma unroll
    for (int i = 0; i < 4; ++i) {
        red[wave][r0 + i][row]      = acc0[i];
        red[wave][r0 + i][16 + row] = acc1[i];
    }
    __syncthreads();

    {
        int r = threadIdx.x >> 5, c = threadIdx.x & 31;
        float s = 0.f;
#pragma unroll
        for (int w = 0; w < 8; ++w) s += red[w][r][c];
        int b = c >> 4, g = c & 15;
        int n = n0 + r;
        out[(size_t)b * (NN * 16) + n * 16 + g] = s + bias[n * 16 + g];
    }
}

extern "C" void kernel_launch(void* const* d_in, const int* in_sizes, int n_in,
                              void* d_out, int out_size, void* d_ws, size_t ws_size,
                              hipStream_t stream) {
    const float* x    = (const float*)d_in[0];
    const float* A    = (const float*)d_in[1];
    const float* ker  = (const float*)d_in[2];
    const float* bias = (const float*)d_in[3];
    float* out = (float*)d_out;
    __hip_bfloat16* hpt = (__hip_bfloat16*)d_ws;   // 32*16384*2B = 1 MB

    fuse_h<<<dim3(NN * 16 / 256), dim3(256), 0, stream>>>(x, ker, hpt);
    gcn_main<<<dim3(NN / 16), dim3(512), 0, stream>>>(A, hpt, bias, out);
}

// Round 3
// 296.497 us; speedup vs baseline: 1.1291x; 1.1291x over previous
//
#include <hip/hip_runtime.h>
#include <hip/hip_bf16.h>

#define NN 16384

typedef __attribute__((ext_vector_type(4))) float  f32x4;
typedef __attribute__((ext_vector_type(8))) short  s16x8;

__device__ inline short bf16_of(float f) {
    return __builtin_bit_cast(short, __float2bfloat16(f));
}

// Kernel 1: HpT[c][m] (bf16), c = b*16+g.  h[b,m,g] = sum_f x[b,m,f]*ker[m,f,g]
__global__ void fuse_h(const float* __restrict__ x, const float* __restrict__ ker,
                       __hip_bfloat16* __restrict__ hpt) {
    int tid = blockIdx.x * 256 + threadIdx.x;
    int g = tid & 15;
    int m = tid >> 4;            // 0..16383
    const float* xb0 = x + m * 16;
    const float* xb1 = x + NN * 16 + m * 16;
    const float* kp  = ker + m * 256 + g;
    float h0 = 0.f, h1 = 0.f;
#pragma unroll
    for (int f = 0; f < 16; ++f) {
        float kk = kp[f * 16];
        h0 += xb0[f] * kk;
        h1 += xb1[f] * kk;
    }
    hpt[g * NN + m]        = __float2bfloat16(h0);
    hpt[(16 + g) * NN + m] = __float2bfloat16(h1);
}

// Kernel 2: out[b,n,g] = sum_m A[n,m]*Hp[m,c] + bias[n,g]
// R1 geometry (1024 blocks x 4 waves, wave K-slice 4096), but K-step 128 with
// an explicit 2-deep register pipeline on the A-stream for memory-level
// parallelism. launch_bounds(256,3): VGPR cap ~170, 3 blocks/CU = 12 waves/CU.
__global__ __launch_bounds__(256, 3) void gcn_main(
        const float* __restrict__ A,
        const __hip_bfloat16* __restrict__ hpt,
        const float* __restrict__ bias,
        float* __restrict__ out) {
    __shared__ float red[4][16][32];

    const int lane = threadIdx.x & 63;
    const int wave = threadIdx.x >> 6;   // 0..3
    const int n0   = blockIdx.x * 16;
    const int row  = lane & 15;          // A row within tile / B col within tile
    const int kg   = lane >> 4;          // 0..3 k-group

    f32x4 acc0 = {0.f, 0.f, 0.f, 0.f};
    f32x4 acc1 = {0.f, 0.f, 0.f, 0.f};

    const int kbase = wave * 4096;
    const float* arow = A + (size_t)(n0 + row) * NN + kbase + kg * 8;
    const __hip_bfloat16* b0r = hpt + row * NN + kbase + kg * 8;  // col-tile 0 (b=0)
    const __hip_bfloat16* b1r = b0r + 16 * NN;                    // col-tile 1 (b=1)

    // Prologue: load A chunk for kk=0 (8 x dwordx4 = 128 k-values across 4 kg)
    f32x4 pc[8], pn[8];
#pragma unroll
    for (int s = 0; s < 4; ++s) {
        pc[2 * s]     = *(const f32x4*)(arow + s * 32);
        pc[2 * s + 1] = *(const f32x4*)(arow + s * 32 + 4);
    }

#pragma unroll 2
    for (int kk = 0; kk < 4096; kk += 128) {
        // Prefetch next A chunk (clamped on the last iteration; re-reads the
        // current L2-hot chunk, negligible)
        const float* apre = arow + ((kk + 128 < 4096) ? kk + 128 : kk);
#pragma unroll
        for (int s = 0; s < 4; ++s) {
            pn[2 * s]     = *(const f32x4*)(apre + s * 32);
            pn[2 * s + 1] = *(const f32x4*)(apre + s * 32 + 4);
        }
        // B fragments for the current chunk (hpt is L2-resident)
        s16x8 bb0[4], bb1[4];
#pragma unroll
        for (int s = 0; s < 4; ++s) {
            bb0[s] = *(const s16x8*)(b0r + kk + s * 32);
            bb1[s] = *(const s16x8*)(b1r + kk + s * 32);
        }
        // Convert current A chunk and do 8 MFMAs (4 k32-steps x 2 col-tiles)
#pragma unroll
        for (int s = 0; s < 4; ++s) {
            s16x8 af;
#pragma unroll
            for (int i = 0; i < 4; ++i) {
                af[i]     = bf16_of(pc[2 * s][i]);
                af[4 + i] = bf16_of(pc[2 * s + 1][i]);
            }
            acc0 = __builtin_amdgcn_mfma_f32_16x16x32_bf16(af, bb0[s], acc0, 0, 0, 0);
            acc1 = __builtin_amdgcn_mfma_f32_16x16x32_bf16(af, bb1[s], acc1, 0, 0, 0);
        }
        // Rotate pipeline (elided by SSA renaming under unroll 2)
#pragma unroll
        for (int i = 0; i < 8; ++i) pc[i] = pn[i];
    }

    // D mapping: col = lane&15, row = (lane>>4)*4 + i
    const int r0 = kg * 4;
#pragma unroll
    for (int i = 0; i < 4; ++i) {
        red[wave][r0 + i][row]      = acc0[i];
        red[wave][r0 + i][16 + row] = acc1[i];
    }
    __syncthreads();

    for (int o = threadIdx.x; o < 512; o += 256) {
        int r = o >> 5, c = o & 31;
        float s = red[0][r][c] + red[1][r][c] + red[2][r][c] + red[3][r][c];
        int b = c >> 4, g = c & 15;
        int n = n0 + r;
        out[(size_t)b * (NN * 16) + n * 16 + g] = s + bias[n * 16 + g];
    }
}

extern "C" void kernel_launch(void* const* d_in, const int* in_sizes, int n_in,
                              void* d_out, int out_size, void* d_ws, size_t ws_size,
                              hipStream_t stream) {
    const float* x    = (const float*)d_in[0];
    const float* A    = (const float*)d_in[1];
    const float* ker  = (const float*)d_in[2];
    const float* bias = (const float*)d_in[3];
    float* out = (float*)d_out;
    __hip_bfloat16* hpt = (__hip_bfloat16*)d_ws;   // 32*16384*2B = 1 MB

    fuse_h<<<dim3(NN * 16 / 256), dim3(256), 0, stream>>>(x, ker, hpt);
    gcn_main<<<dim3(NN / 16), dim3(256), 0, stream>>>(A, hpt, bias, out);
}

// Round 4
// 274.827 us; speedup vs baseline: 1.2181x; 1.0788x over previous
//
#include <hip/hip_runtime.h>
#include <hip/hip_bf16.h>

#define NN 16384

typedef __attribute__((ext_vector_type(4))) float  f32x4;
typedef __attribute__((ext_vector_type(8))) short  s16x8;

__device__ inline short bf16_of(float f) {
    return __builtin_bit_cast(short, __float2bfloat16(f));
}

// Kernel 1: HpT[c][m] (bf16), c = b*16+g.  h[b,m,g] = sum_f x[b,m,f]*ker[m,f,g]
__global__ void fuse_h(const float* __restrict__ x, const float* __restrict__ ker,
                       __hip_bfloat16* __restrict__ hpt) {
    int tid = blockIdx.x * 256 + threadIdx.x;
    int g = tid & 15;
    int m = tid >> 4;            // 0..16383
    const float* xb0 = x + m * 16;
    const float* xb1 = x + NN * 16 + m * 16;
    const float* kp  = ker + m * 256 + g;
    float h0 = 0.f, h1 = 0.f;
#pragma unroll
    for (int f = 0; f < 16; ++f) {
        float kk = kp[f * 16];
        h0 += xb0[f] * kk;
        h1 += xb1[f] * kk;
    }
    hpt[g * NN + m]        = __float2bfloat16(h0);
    hpt[(16 + g) * NN + m] = __float2bfloat16(h1);
}

// Kernel 2: partial[ks][n][c] = sum_{m in ks-slice} A[n,m]*Hp[m,c]
// Grid 1024 = 256 rowBlocks x 4 K-splits. Block: 256 thr = 4 waves, owns 64
// rows x 4096 k. Wave w handles k-slice of 1024. Each wave: 4 row-tiles x
// 2 col-tiles -> each B fragment feeds 4 MFMAs (hpt traffic 1GB -> 256MB).
__global__ __launch_bounds__(256, 4) void gcn_partial(
        const float* __restrict__ A,
        const __hip_bfloat16* __restrict__ hpt,
        float* __restrict__ part) {
    __shared__ float red[4][64][33];

    const int lane = threadIdx.x & 63;
    const int wave = threadIdx.x >> 6;   // 0..3
    const int rowBlk = blockIdx.x >> 2;
    const int ks     = blockIdx.x & 3;
    const int n0   = rowBlk * 64;
    const int row  = lane & 15;
    const int kg   = lane >> 4;          // 0..3

    f32x4 acc[4][2];
#pragma unroll
    for (int t = 0; t < 4; ++t)
#pragma unroll
        for (int c = 0; c < 2; ++c) acc[t][c] = (f32x4){0.f, 0.f, 0.f, 0.f};

    const int kbase = ks * 4096 + wave * 1024;
    const float* a0 = A + (size_t)(n0 + row) * NN + kbase + kg * 8;
    const __hip_bfloat16* b0r = hpt + row * NN + kbase + kg * 8;  // c-tile 0
    const __hip_bfloat16* b1r = b0r + 16 * NN;                    // c-tile 1

    for (int kk = 0; kk < 1024; kk += 32) {
        // B fragments first (L2-resident hpt) so counted waits for B do not
        // have to drain A loads.
        s16x8 bb0 = *(const s16x8*)(b0r + kk);
        s16x8 bb1 = *(const s16x8*)(b1r + kk);

        // Half 0: row-tiles 0,1  (A is streamed once: non-temporal)
        f32x4 p0 = __builtin_nontemporal_load((const f32x4*)(a0 + kk));
        f32x4 p1 = __builtin_nontemporal_load((const f32x4*)(a0 + kk + 4));
        f32x4 p2 = __builtin_nontemporal_load((const f32x4*)(a0 + 16 * NN + kk));
        f32x4 p3 = __builtin_nontemporal_load((const f32x4*)(a0 + 16 * NN + kk + 4));
        s16x8 af0, af1;
#pragma unroll
        for (int i = 0; i < 4; ++i) {
            af0[i] = bf16_of(p0[i]); af0[4 + i] = bf16_of(p1[i]);
            af1[i] = bf16_of(p2[i]); af1[4 + i] = bf16_of(p3[i]);
        }
        acc[0][0] = __builtin_amdgcn_mfma_f32_16x16x32_bf16(af0, bb0, acc[0][0], 0, 0, 0);
        acc[0][1] = __builtin_amdgcn_mfma_f32_16x16x32_bf16(af0, bb1, acc[0][1], 0, 0, 0);
        acc[1][0] = __builtin_amdgcn_mfma_f32_16x16x32_bf16(af1, bb0, acc[1][0], 0, 0, 0);
        acc[1][1] = __builtin_amdgcn_mfma_f32_16x16x32_bf16(af1, bb1, acc[1][1], 0, 0, 0);

        // Half 1: row-tiles 2,3
        f32x4 q0 = __builtin_nontemporal_load((const f32x4*)(a0 + 32 * NN + kk));
        f32x4 q1 = __builtin_nontemporal_load((const f32x4*)(a0 + 32 * NN + kk + 4));
        f32x4 q2 = __builtin_nontemporal_load((const f32x4*)(a0 + 48 * NN + kk));
        f32x4 q3 = __builtin_nontemporal_load((const f32x4*)(a0 + 48 * NN + kk + 4));
        s16x8 ag0, ag1;
#pragma unroll
        for (int i = 0; i < 4; ++i) {
            ag0[i] = bf16_of(q0[i]); ag0[4 + i] = bf16_of(q1[i]);
            ag1[i] = bf16_of(q2[i]); ag1[4 + i] = bf16_of(q3[i]);
        }
        acc[2][0] = __builtin_amdgcn_mfma_f32_16x16x32_bf16(ag0, bb0, acc[2][0], 0, 0, 0);
        acc[2][1] = __builtin_amdgcn_mfma_f32_16x16x32_bf16(ag0, bb1, acc[2][1], 0, 0, 0);
        acc[3][0] = __builtin_amdgcn_mfma_f32_16x16x32_bf16(ag1, bb0, acc[3][0], 0, 0, 0);
        acc[3][1] = __builtin_amdgcn_mfma_f32_16x16x32_bf16(ag1, bb1, acc[3][1], 0, 0, 0);
    }

    // D mapping: col = lane&15, row = (lane>>4)*4 + i
#pragma unroll
    for (int t = 0; t < 4; ++t)
#pragma unroll
        for (int i = 0; i < 4; ++i) {
            red[wave][t * 16 + kg * 4 + i][row]      = acc[t][0][i];
            red[wave][t * 16 + kg * 4 + i][16 + row] = acc[t][1][i];
        }
    __syncthreads();

    float* pb = part + (size_t)ks * (NN * 32) + (size_t)n0 * 32;
    for (int o = threadIdx.x; o < 64 * 32; o += 256) {
        int r = o >> 5, c = o & 31;
        pb[o] = red[0][r][c] + red[1][r][c] + red[2][r][c] + red[3][r][c];
    }
}

// Kernel 3: out[b,n,g] = sum_ks part[ks][n][c] + bias[n,g]
__global__ void gcn_reduce(const float* __restrict__ part,
                           const float* __restrict__ bias,
                           float* __restrict__ out) {
    int idx = blockIdx.x * 256 + threadIdx.x;   // over 16384*32
    int n = idx >> 5, c = idx & 31;
    int b = c >> 4, g = c & 15;
    float s = part[idx] + part[idx + NN * 32] + part[idx + 2 * NN * 32]
            + part[idx + 3 * NN * 32];
    out[(size_t)b * (NN * 16) + n * 16 + g] = s + bias[n * 16 + g];
}

extern "C" void kernel_launch(void* const* d_in, const int* in_sizes, int n_in,
                              void* d_out, int out_size, void* d_ws, size_t ws_size,
                              hipStream_t stream) {
    const float* x    = (const float*)d_in[0];
    const float* A    = (const float*)d_in[1];
    const float* ker  = (const float*)d_in[2];
    const float* bias = (const float*)d_in[3];
    float* out = (float*)d_out;
    __hip_bfloat16* hpt = (__hip_bfloat16*)d_ws;            // 1 MB
    float* part = (float*)((char*)d_ws + (1 << 20));        // 4*16384*32*4 = 8 MB

    fuse_h<<<dim3(NN * 16 / 256), dim3(256), 0, stream>>>(x, ker, hpt);
    gcn_partial<<<dim3(1024), dim3(256), 0, stream>>>(A, hpt, part);
    gcn_reduce<<<dim3(NN * 32 / 256), dim3(256), 0, stream>>>(part, bias, out);
}

// Round 5
// 229.447 us; speedup vs baseline: 1.4590x; 1.1978x over previous
//
#include <hip/hip_runtime.h>
#include <hip/hip_bf16.h>

#define NN 16384

typedef __attribute__((ext_vector_type(4))) float  f32x4;
typedef __attribute__((ext_vector_type(8))) short  s16x8;
typedef __attribute__((ext_vector_type(4))) short  s16x4;

__device__ inline short bf16_of(float f) {
    return __builtin_bit_cast(short, __float2bfloat16(f));
}

// Kernel 1: HpT[c][m] (bf16), c = b*16+g.  h[b,m,g] = sum_f x[b,m,f]*ker[m,f,g]
__global__ void fuse_h(const float* __restrict__ x, const float* __restrict__ ker,
                       __hip_bfloat16* __restrict__ hpt) {
    int tid = blockIdx.x * 256 + threadIdx.x;
    int g = tid & 15;
    int m = tid >> 4;            // 0..16383
    const float* xb0 = x + m * 16;
    const float* xb1 = x + NN * 16 + m * 16;
    const float* kp  = ker + m * 256 + g;
    float h0 = 0.f, h1 = 0.f;
#pragma unroll
    for (int f = 0; f < 16; ++f) {
        float kk = kp[f * 16];
        h0 += xb0[f] * kk;
        h1 += xb1[f] * kk;
    }
    hpt[g * NN + m]        = __float2bfloat16(h0);
    hpt[(16 + g) * NN + m] = __float2bfloat16(h1);
}

// Kernel 2: partial[ks][n][c] = sum_{m in ks-slice} A[n,m]*Hp[m,c]
// Grid 1024 = 256 rowBlocks x 4 K-splits; 4 waves/block, ZERO barriers.
// Wave owns 16 output rows x 32 cols x 4096 k. Per K-step (128 cols) the wave
// stages its 16x128 fp32 A-chunk through a private 4KB LDS tile using
// CONTIGUOUS 512B-per-row global bursts (DRAM page locality), converts to
// bf16, then ds_read_b128 the MFMA fragments (XOR-swizzled, conflict-free).
__global__ __launch_bounds__(256, 4) void gcn_partial(
        const float* __restrict__ A,
        const __hip_bfloat16* __restrict__ hpt,
        float* __restrict__ part) {
    __shared__ __attribute__((aligned(16))) char tile[4][4096];

    const int lane = threadIdx.x & 63;
    const int wave = threadIdx.x >> 6;   // 0..3
    const int rowBlk = blockIdx.x >> 2;
    const int ks     = blockIdx.x & 3;
    const int n0     = rowBlk * 64 + wave * 16;  // wave's 16 rows
    const int kbase  = ks * 4096;

    // staging roles: lanes 0..31 -> even row of pair, 32..63 -> odd row
    const int half = lane >> 5;
    const int c4   = (lane & 31) << 2;   // float col within 128-step
    const int wby  = (lane & 31) << 3;   // LDS byte col for 4-bf16 write
    // consume roles (MFMA fragment)
    const int row  = lane & 15;
    const int kg   = lane >> 4;

    char* lds = tile[wave];

    f32x4 acc0 = {0.f, 0.f, 0.f, 0.f};
    f32x4 acc1 = {0.f, 0.f, 0.f, 0.f};
    f32x4 st[8];

    const float* abase = A + (size_t)n0 * NN + kbase;
    const __hip_bfloat16* b0base = hpt + row * NN + kbase + kg * 8; // c-tile 0
    const __hip_bfloat16* b1base = b0base + 16 * NN;                // c-tile 1

    // ---- prologue: stage K-step 0 ----
#pragma unroll
    for (int r = 0; r < 8; ++r) {
        int row_l = 2 * r + half;
        st[r] = __builtin_nontemporal_load(
                    (const f32x4*)(abase + (size_t)row_l * NN + c4));
    }
#pragma unroll
    for (int r = 0; r < 8; ++r) {
        int row_l = 2 * r + half;
        int byte = (row_l * 256 + wby) ^ ((row_l & 7) << 4);
        s16x4 v;
        v[0] = bf16_of(st[r][0]); v[1] = bf16_of(st[r][1]);
        v[2] = bf16_of(st[r][2]); v[3] = bf16_of(st[r][3]);
        *(s16x4*)(lds + byte) = v;
    }

    for (int t = 0; t < 32; ++t) {
        // B fragments FIRST (L2-resident): their vmcnt wait must not drain
        // the A prefetch issued below (vmcnt is in-order).
        s16x8 bb0[4], bb1[4];
#pragma unroll
        for (int j = 0; j < 4; ++j) {
            bb0[j] = *(const s16x8*)(b0base + t * 128 + j * 32);
            bb1[j] = *(const s16x8*)(b1base + t * 128 + j * 32);
        }
        // A prefetch for t+1 (clamped re-read on last iter, harmless)
        const float* ap = abase + (t < 31 ? (t + 1) : t) * 128 + c4;
#pragma unroll
        for (int r = 0; r < 8; ++r) {
            int row_l = 2 * r + half;
            st[r] = __builtin_nontemporal_load(
                        (const f32x4*)(ap + (size_t)row_l * NN));
        }
        // consume tile t from LDS
#pragma unroll
        for (int j = 0; j < 4; ++j) {
            int byte = (row * 256 + j * 64 + kg * 16) ^ ((row & 7) << 4);
            s16x8 af = *(const s16x8*)(lds + byte);
            acc0 = __builtin_amdgcn_mfma_f32_16x16x32_bf16(af, bb0[j], acc0, 0, 0, 0);
            acc1 = __builtin_amdgcn_mfma_f32_16x16x32_bf16(af, bb1[j], acc1, 0, 0, 0);
        }
        // convert + write tile t+1 (after consume; same-wave ds order is safe)
#pragma unroll
        for (int r = 0; r < 8; ++r) {
            int row_l = 2 * r + half;
            int byte = (row_l * 256 + wby) ^ ((row_l & 7) << 4);
            s16x4 v;
            v[0] = bf16_of(st[r][0]); v[1] = bf16_of(st[r][1]);
            v[2] = bf16_of(st[r][2]); v[3] = bf16_of(st[r][3]);
            *(s16x4*)(lds + byte) = v;
        }
    }

    // D mapping: col = lane&15 (B col), row = kg*4 + i (A row)
    float* pb = part + (size_t)ks * (NN * 32);
#pragma unroll
    for (int i = 0; i < 4; ++i) {
        int n = n0 + kg * 4 + i;
        pb[n * 32 + row]      = acc0[i];
        pb[n * 32 + 16 + row] = acc1[i];
    }
}

// Kernel 3: out[b,n,g] = sum_ks part[ks][n][c] + bias[n,g]
__global__ void gcn_reduce(const float* __restrict__ part,
                           const float* __restrict__ bias,
                           float* __restrict__ out) {
    int idx = blockIdx.x * 256 + threadIdx.x;   // over 16384*32
    int n = idx >> 5, c = idx & 31;
    int b = c >> 4, g = c & 15;
    float s = part[idx] + part[idx + NN * 32] + part[idx + 2 * NN * 32]
            + part[idx + 3 * NN * 32];
    out[(size_t)b * (NN * 16) + n * 16 + g] = s + bias[n * 16 + g];
}

extern "C" void kernel_launch(void* const* d_in, const int* in_sizes, int n_in,
                              void* d_out, int out_size, void* d_ws, size_t ws_size,
                              hipStream_t stream) {
    const float* x    = (const float*)d_in[0];
    const float* A    = (const float*)d_in[1];
    const float* ker  = (const float*)d_in[2];
    const float* bias = (const float*)d_in[3];
    float* out = (float*)d_out;
    __hip_bfloat16* hpt = (__hip_bfloat16*)d_ws;            // 1 MB
    float* part = (float*)((char*)d_ws + (1 << 20));        // 8 MB

    fuse_h<<<dim3(NN * 16 / 256), dim3(256), 0, stream>>>(x, ker, hpt);
    gcn_partial<<<dim3(1024), dim3(256), 0, stream>>>(A, hpt, part);
    gcn_reduce<<<dim3(NN * 32 / 256), dim3(256), 0, stream>>>(part, bias, out);
}

// Round 6
// 222.685 us; speedup vs baseline: 1.5033x; 1.0304x over previous
//
#include <hip/hip_runtime.h>
#include <hip/hip_bf16.h>

#define NN 16384

typedef __attribute__((ext_vector_type(4))) float  f32x4;
typedef __attribute__((ext_vector_type(8))) short  s16x8;
typedef __attribute__((ext_vector_type(4))) short  s16x4;

__device__ inline short bf16_of(float f) {
    return __builtin_bit_cast(short, __float2bfloat16(f));
}

// Kernel 1: HpT[c][m] (bf16), c = b*16+g.  h[b,m,g] = sum_f x[b,m,f]*ker[m,f,g]
__global__ void fuse_h(const float* __restrict__ x, const float* __restrict__ ker,
                       __hip_bfloat16* __restrict__ hpt) {
    int tid = blockIdx.x * 256 + threadIdx.x;
    int g = tid & 15;
    int m = tid >> 4;            // 0..16383
    const float* xb0 = x + m * 16;
    const float* xb1 = x + NN * 16 + m * 16;
    const float* kp  = ker + m * 256 + g;
    float h0 = 0.f, h1 = 0.f;
#pragma unroll
    for (int f = 0; f < 16; ++f) {
        float kk = kp[f * 16];
        h0 += xb0[f] * kk;
        h1 += xb1[f] * kk;
    }
    hpt[g * NN + m]        = __float2bfloat16(h0);
    hpt[(16 + g) * NN + m] = __float2bfloat16(h1);
}

// Kernel 2: partial[ks][n][c] = sum_{m in ks-slice} A[n,m]*Hp[m,c]
// Grid 1024 = 256 rowBlocks x 4 K-splits; 4 waves/block, ZERO barriers.
// Wave owns 16 rows x 32 cols x 4096 k. K-step = 256 floats: each staging
// load instruction is 64 lanes x 16B = ONE fully-contiguous 1KB burst from a
// single A row (fill-kernel DRAM pattern). Wave-private 8KB LDS tile decouples
// the burst layout from the MFMA fragment layout (XOR-swizzled).
__global__ __launch_bounds__(256, 4) void gcn_partial(
        const float* __restrict__ A,
        const __hip_bfloat16* __restrict__ hpt,
        float* __restrict__ part) {
    __shared__ __attribute__((aligned(16))) char tile[4][8192];

    const int lane = threadIdx.x & 63;
    const int wave = threadIdx.x >> 6;   // 0..3
    const int rowBlk = blockIdx.x >> 2;
    const int ks     = blockIdx.x & 3;
    const int n0     = rowBlk * 64 + wave * 16;  // wave's 16 rows
    const int kbase  = ks * 4096;

    // consume roles (MFMA fragment)
    const int row  = lane & 15;
    const int kg   = lane >> 4;

    char* lds = tile[wave];

    f32x4 acc0 = {0.f, 0.f, 0.f, 0.f};
    f32x4 acc1 = {0.f, 0.f, 0.f, 0.f};
    f32x4 st[16];

    const float* abase = A + (size_t)n0 * NN + kbase;
    const __hip_bfloat16* b0base = hpt + row * NN + kbase + kg * 8; // c-tile 0
    const __hip_bfloat16* b1base = b0base + 16 * NN;                // c-tile 1

    // ---- prologue: stage K-step 0 (16 x 1KB single-row bursts) ----
#pragma unroll
    for (int r = 0; r < 16; ++r)
        st[r] = __builtin_nontemporal_load(
                    (const f32x4*)(abase + (size_t)r * NN + lane * 4));
#pragma unroll
    for (int r = 0; r < 16; ++r) {
        int byte = (r * 512 + lane * 8) ^ ((r & 7) << 4);
        s16x4 v;
        v[0] = bf16_of(st[r][0]); v[1] = bf16_of(st[r][1]);
        v[2] = bf16_of(st[r][2]); v[3] = bf16_of(st[r][3]);
        *(s16x4*)(lds + byte) = v;
    }

#pragma unroll 1
    for (int t = 0; t < 16; ++t) {
        // B half-0 FIRST (L2-resident): its counted vmcnt wait must not drain
        // the A prefetch issued below (vmcnt is in-order).
        s16x8 bb0[4], bb1[4];
#pragma unroll
        for (int j = 0; j < 4; ++j) {
            bb0[j] = *(const s16x8*)(b0base + t * 256 + j * 32);
            bb1[j] = *(const s16x8*)(b1base + t * 256 + j * 32);
        }
        // A prefetch for t+1 (guarded: no clamp re-reads)
        if (t < 15) {
            const float* ap = abase + (t + 1) * 256 + lane * 4;
#pragma unroll
            for (int r = 0; r < 16; ++r)
                st[r] = __builtin_nontemporal_load(
                            (const f32x4*)(ap + (size_t)r * NN));
        }
        // consume half-0 of tile t from LDS (waits only on B half-0)
#pragma unroll
        for (int j = 0; j < 4; ++j) {
            int byte = (row * 512 + j * 64 + kg * 16) ^ ((row & 7) << 4);
            s16x8 af = *(const s16x8*)(lds + byte);
            acc0 = __builtin_amdgcn_mfma_f32_16x16x32_bf16(af, bb0[j], acc0, 0, 0, 0);
            acc1 = __builtin_amdgcn_mfma_f32_16x16x32_bf16(af, bb1[j], acc1, 0, 0, 0);
        }
        // B half-1 (issued after A; consuming it drains A, which the write
        // below needs anyway -- single stall point per iteration)
        s16x8 cb0[4], cb1[4];
#pragma unroll
        for (int j = 0; j < 4; ++j) {
            cb0[j] = *(const s16x8*)(b0base + t * 256 + 128 + j * 32);
            cb1[j] = *(const s16x8*)(b1base + t * 256 + 128 + j * 32);
        }
#pragma unroll
        for (int j = 0; j < 4; ++j) {
            int byte = (row * 512 + 256 + j * 64 + kg * 16) ^ ((row & 7) << 4);
            s16x8 af = *(const s16x8*)(lds + byte);
            acc0 = __builtin_amdgcn_mfma_f32_16x16x32_bf16(af, cb0[j], acc0, 0, 0, 0);
            acc1 = __builtin_amdgcn_mfma_f32_16x16x32_bf16(af, cb1[j], acc1, 0, 0, 0);
        }
        // convert + write tile t+1 (A already drained; wave-private, no barrier)
        if (t < 15) {
#pragma unroll
            for (int r = 0; r < 16; ++r) {
                int byte = (r * 512 + lane * 8) ^ ((r & 7) << 4);
                s16x4 v;
                v[0] = bf16_of(st[r][0]); v[1] = bf16_of(st[r][1]);
                v[2] = bf16_of(st[r][2]); v[3] = bf16_of(st[r][3]);
                *(s16x4*)(lds + byte) = v;
            }
        }
    }

    // D mapping: col = lane&15 (B col), row = kg*4 + i (A row)
    float* pb = part + (size_t)ks * (NN * 32);
#pragma unroll
    for (int i = 0; i < 4; ++i) {
        int n = n0 + kg * 4 + i;
        pb[n * 32 + row]      = acc0[i];
        pb[n * 32 + 16 + row] = acc1[i];
    }
}

// Kernel 3: out[b,n,g] = sum_ks part[ks][n][c] + bias[n,g]
__global__ void gcn_reduce(const float* __restrict__ part,
                           const float* __restrict__ bias,
                           float* __restrict__ out) {
    int idx = blockIdx.x * 256 + threadIdx.x;   // over 16384*32
    int n = idx >> 5, c = idx & 31;
    int b = c >> 4, g = c & 15;
    float s = part[idx] + part[idx + NN * 32] + part[idx + 2 * NN * 32]
            + part[idx + 3 * NN * 32];
    out[(size_t)b * (NN * 16) + n * 16 + g] = s + bias[n * 16 + g];
}

extern "C" void kernel_launch(void* const* d_in, const int* in_sizes, int n_in,
                              void* d_out, int out_size, void* d_ws, size_t ws_size,
                              hipStream_t stream) {
    const float* x    = (const float*)d_in[0];
    const float* A    = (const float*)d_in[1];
    const float* ker  = (const float*)d_in[2];
    const float* bias = (const float*)d_in[3];
    float* out = (float*)d_out;
    __hip_bfloat16* hpt = (__hip_bfloat16*)d_ws;            // 1 MB
    float* part = (float*)((char*)d_ws + (1 << 20));        // 8 MB

    fuse_h<<<dim3(NN * 16 / 256), dim3(256), 0, stream>>>(x, ker, hpt);
    gcn_partial<<<dim3(1024), dim3(256), 0, stream>>>(A, hpt, part);
    gcn_reduce<<<dim3(NN * 32 / 256), dim3(256), 0, stream>>>(part, bias, out);
}